// Round 2
// baseline (595.399 us; speedup 1.0000x reference)
//
#include <hip/hip_runtime.h>
#include <hip/hip_bf16.h>
#include <stdint.h>

#define NP 409600
#define HG 640
#define WG 640
#define HW (HG*WG)
// spatial tiles: 16x16 cells, ~50% density => ~128 points/tile = one conv block
#define TPB  40          // tiles per axis (640/16)
#define NTILE 3200       // 2 * 40 * 40

typedef __bf16 bf16x8 __attribute__((ext_vector_type(8)));
typedef float f32x4 __attribute__((ext_vector_type(4)));

// ---------------- prep kernels ----------------

// counting sort by spatial tile: hist -> exclusive scan -> scatter order
__global__ void hist_kernel(const int* __restrict__ coords, int* __restrict__ hist) {
    int i = blockIdx.x * 256 + threadIdx.x;
    int b = coords[3*i], y = coords[3*i+1], x = coords[3*i+2];
    atomicAdd(&hist[b*(TPB*TPB) + (y>>4)*TPB + (x>>4)], 1);
}

__global__ void scan_kernel(int* __restrict__ hist) {   // 1 block, 256 threads, 13 vals each
    __shared__ int part[256];
    int t = threadIdx.x;
    int loc[13];
    int s = 0;
    #pragma unroll
    for (int k = 0; k < 13; ++k) {
        int idx = t*13 + k;
        int v = (idx < NTILE) ? hist[idx] : 0;
        loc[k] = s; s += v;
    }
    part[t] = s;
    __syncthreads();
    for (int off = 1; off < 256; off <<= 1) {   // Hillis-Steele inclusive scan
        int v = (t >= off) ? part[t - off] : 0;
        __syncthreads();
        part[t] += v;
        __syncthreads();
    }
    int pre = (t > 0) ? part[t-1] : 0;
    #pragma unroll
    for (int k = 0; k < 13; ++k) {
        int idx = t*13 + k;
        if (idx < NTILE) hist[idx] = pre + loc[k];
    }
}

// ord[pos] = original point id; lsort[pos] = packed linear coord
__global__ void ord_kernel(const int* __restrict__ coords, int* __restrict__ offs,
                           int* __restrict__ ord, int* __restrict__ lsort) {
    int i = blockIdx.x * 256 + threadIdx.x;
    int b = coords[3*i], y = coords[3*i+1], x = coords[3*i+2];
    int tile = b*(TPB*TPB) + (y>>4)*TPB + (x>>4);
    int pos = atomicAdd(&offs[tile], 1);
    ord[pos]   = i;
    lsort[pos] = b*HW + y*WG + x;
}

// grid[lin] = SORTED position (so nbr table holds sorted positions)
__global__ void scatter_sorted_kernel(const int* __restrict__ lsort, int* __restrict__ grid) {
    int j = blockIdx.x * 256 + threadIdx.x;
    grid[lsort[j]] = j;
}

// permute + cast: fpermb[j] = bf16(features[ord[j]]); 8 threads per row
__global__ void perm_cast_kernel(const float* __restrict__ f, const int* __restrict__ ord,
                                 __hip_bfloat16* __restrict__ fpermb) {
    int t = blockIdx.x * 256 + threadIdx.x;       // grid = 12800 blocks
    int j = t >> 3, part = t & 7;
    int i = ord[j];
    const float4* p = (const float4*)(f + (long)i*64 + part*8);
    float4 a = p[0], b = p[1];
    union { uint4 q; __hip_bfloat16 h[8]; } u;
    u.h[0] = __float2bfloat16(a.x); u.h[1] = __float2bfloat16(a.y);
    u.h[2] = __float2bfloat16(a.z); u.h[3] = __float2bfloat16(a.w);
    u.h[4] = __float2bfloat16(b.x); u.h[5] = __float2bfloat16(b.y);
    u.h[6] = __float2bfloat16(b.z); u.h[7] = __float2bfloat16(b.w);
    *(uint4*)(fpermb + (long)j*64 + part*8) = u.q;
}

// neighbor table over SORTED order j; center tap (tt==4) omitted (always self).
// values are SORTED positions (index fpermb / y1 directly)
__global__ void nbr_kernel(const int* __restrict__ lsort, const int* __restrict__ grid,
                           int* __restrict__ nbrp) {
    int j = blockIdx.x * 256 + threadIdx.x;
    int lin = lsort[j];
    int b = lin / HW;
    int rem = lin - b*HW;
    int y = rem / WG;
    int x = rem - y*WG;
    int baseg = b*HW;
    #pragma unroll
    for (int tt = 0; tt < 9; ++tt) {
        if (tt == 4) continue;
        int ti = tt < 4 ? tt : tt - 1;
        int ny = y + tt/3 - 1, nx = x + tt%3 - 1;
        int g = -1;
        if (ny >= 0 && ny < HG && nx >= 0 && nx < WG)
            g = grid[baseg + ny*WG + nx];
        nbrp[ti*NP + j] = g;
    }
}

// weights pre-cast to bf16 and transposed to [tap][n=out_ch][k=in_ch]
__global__ void cast_w_kernel(const float* __restrict__ w1, const float* __restrict__ w2,
                              const float* __restrict__ wd,
                              __hip_bfloat16* __restrict__ wc1, __hip_bfloat16* __restrict__ wc2) {
    int i = blockIdx.x * 256 + threadIdx.x;   // grid = 77824 threads exactly
    if (i < 9*4096) {
        int t = i >> 12, r = i & 4095, n = r >> 6, k = r & 63;
        wc1[i] = __float2bfloat16(w1[(t << 12) + (k << 6) + n]);
    }
    int j = i - 9*4096;
    if (j >= 0 && j < 10*4096) {
        int t = j >> 12, r = j & 4095, n = r >> 6, k = r & 63;
        float v = (t < 9) ? w2[(t << 12) + (k << 6) + n] : wd[(k << 6) + n];
        wc2[j] = __float2bfloat16(v);
    }
}

// ---------------- gather-GEMM conv kernel ----------------
// Tile: 128 sorted rows x 64 cols per block, 256 threads = 4 waves.
// Data is in SORTED order (fpermb / y1) so gathers are L2-local.
// Register prefetch pipeline: tap t+1's A rows + B tile are loaded into
// regs while tap t's MFMAs run; written to LDS after the barrier.
// FINAL: tap 9 = identity(fpermb, contiguous) @ wd into separate accR
// (reference applies relu(conv2+b2) BEFORE adding the residual).

#define LDA 72
#define LDB 72

template<bool FINAL>
__launch_bounds__(256, 4)
__global__ void conv_kernel(const __hip_bfloat16* __restrict__ src,    // sorted-order gather source
                            const __hip_bfloat16* __restrict__ idsrc,  // identity source (FINAL)
                            const int* __restrict__ nbrp,              // [8][NP] sorted positions
                            const int* __restrict__ ord,               // sorted pos -> orig id
                            const __hip_bfloat16* __restrict__ wT,     // [NTAP][64][64] (n,k)
                            const float* __restrict__ bias,
                            __hip_bfloat16* __restrict__ out_bf,       // sorted order (conv1)
                            float* __restrict__ out_f) {               // original order (conv2)
    __shared__ __align__(16) __hip_bfloat16 As[128 * LDA];
    __shared__ __align__(16) __hip_bfloat16 Bs[64 * LDB];

    const int tid = threadIdx.x;
    // XCD-aware swizzle: 3200 blocks, 8 XCDs, 400 contiguous spatial tiles per XCD
    const int sbid = (blockIdx.x & 7) * 400 + (blockIdx.x >> 3);
    const int base = sbid * 128;
    const int wave = tid >> 6, lane = tid & 63;
    const int srow = tid >> 1, shalf = tid & 1;   // staging: 2 threads per row

    f32x4 acc[2][4];
    f32x4 accR[2][4];
    #pragma unroll
    for (int i = 0; i < 2; ++i)
        #pragma unroll
        for (int j = 0; j < 4; ++j) {
            acc[i][j]  = (f32x4){0.f, 0.f, 0.f, 0.f};
            accR[i][j] = (f32x4){0.f, 0.f, 0.f, 0.f};
        }

    // prefetch registers
    uint4 v0, v1, v2, v3;       // A rows
    uint4 w0, w1;               // B tile

    auto gpos = [&](int t) -> int {
        if (t == 4) return base + srow;                   // center tap = self
        int ti = t < 4 ? t : t - 1;
        return nbrp[ti*NP + base + srow];
    };
    auto issueA = [&](const __hip_bfloat16* sp, int g) {
        if (g >= 0) {
            const uint4* p = (const uint4*)(sp + (long)g*64 + shalf*32);
            v0 = p[0]; v1 = p[1]; v2 = p[2]; v3 = p[3];
        } else {
            v0 = v1 = v2 = v3 = make_uint4(0u, 0u, 0u, 0u);
        }
    };
    auto issueB = [&](int t) {
        const uint4* wp = (const uint4*)(wT + t*4096);
        w0 = wp[tid]; w1 = wp[tid + 256];
    };
    auto writeA = [&]() {
        uint4* dst = (uint4*)(As + srow*LDA + shalf*32);
        dst[0] = v0; dst[1] = v1; dst[2] = v2; dst[3] = v3;
    };
    auto writeB = [&]() {
        #pragma unroll
        for (int jj = 0; jj < 2; ++jj) {
            int l = (tid + jj*256) * 8;
            int n = l >> 6, k = l & 63;
            *(uint4*)(Bs + n*LDB + k) = (jj == 0) ? w0 : w1;
        }
    };
    auto do_mfma = [&](f32x4 (&ac)[2][4]) {
        #pragma unroll
        for (int ks = 0; ks < 2; ++ks) {
            int kb = ks*32 + (lane >> 4)*8;
            bf16x8 a0 = *(const bf16x8*)(As + (wave*32      + (lane & 15))*LDA + kb);
            bf16x8 a1 = *(const bf16x8*)(As + (wave*32 + 16 + (lane & 15))*LDA + kb);
            bf16x8 b0 = *(const bf16x8*)(Bs + ( 0 + (lane & 15))*LDB + kb);
            bf16x8 b1 = *(const bf16x8*)(Bs + (16 + (lane & 15))*LDB + kb);
            bf16x8 b2 = *(const bf16x8*)(Bs + (32 + (lane & 15))*LDB + kb);
            bf16x8 b3 = *(const bf16x8*)(Bs + (48 + (lane & 15))*LDB + kb);
            ac[0][0] = __builtin_amdgcn_mfma_f32_16x16x32_bf16(a0, b0, ac[0][0], 0, 0, 0);
            ac[0][1] = __builtin_amdgcn_mfma_f32_16x16x32_bf16(a0, b1, ac[0][1], 0, 0, 0);
            ac[0][2] = __builtin_amdgcn_mfma_f32_16x16x32_bf16(a0, b2, ac[0][2], 0, 0, 0);
            ac[0][3] = __builtin_amdgcn_mfma_f32_16x16x32_bf16(a0, b3, ac[0][3], 0, 0, 0);
            ac[1][0] = __builtin_amdgcn_mfma_f32_16x16x32_bf16(a1, b0, ac[1][0], 0, 0, 0);
            ac[1][1] = __builtin_amdgcn_mfma_f32_16x16x32_bf16(a1, b1, ac[1][1], 0, 0, 0);
            ac[1][2] = __builtin_amdgcn_mfma_f32_16x16x32_bf16(a1, b2, ac[1][2], 0, 0, 0);
            ac[1][3] = __builtin_amdgcn_mfma_f32_16x16x32_bf16(a1, b3, ac[1][3], 0, 0, 0);
        }
    };

    const int NT = FINAL ? 10 : 9;

    issueA(src, gpos(0));
    issueB(0);

    for (int t = 0; t < NT; ++t) {
        if (t) __syncthreads();   // WAR: previous tap's mfma reads done
        writeA();
        writeB();
        __syncthreads();
        // prefetch next tap while this tap's MFMAs run (regs only, no LDS hazard)
        if (t + 1 < NT) {
            if (FINAL && t + 1 == 9) issueA(idsrc, base + srow);
            else                     issueA(src, gpos(t + 1));
            issueB(t + 1);
        }
        if (FINAL && t == 9) do_mfma(accR);
        else                 do_mfma(acc);
    }

    // ---- epilogue ----
    const int col = lane & 15, quad = lane >> 4;
    #pragma unroll
    for (int cb = 0; cb < 4; ++cb) {
        float bv = bias[cb*16 + col];
        #pragma unroll
        for (int mb = 0; mb < 2; ++mb) {
            #pragma unroll
            for (int r = 0; r < 4; ++r) {
                float v = acc[mb][cb][r] + bv;
                v = v > 0.f ? v : 0.f;
                int srt = base + wave*32 + mb*16 + quad*4 + r;   // sorted row
                int c   = cb*16 + col;
                if (FINAL) {
                    v += accR[mb][cb][r];      // residual added AFTER inner relu
                    v = v > 0.f ? v : 0.f;
                    long row = ord[srt];       // scatter to original order
                    out_f[row*64 + c] = v;
                } else {
                    out_bf[(long)srt*64 + c] = __float2bfloat16(v);   // stay sorted
                }
            }
        }
    }
}

// ---------------- launch ----------------

extern "C" void kernel_launch(void* const* d_in, const int* in_sizes, int n_in,
                              void* d_out, int out_size, void* d_ws, size_t ws_size,
                              hipStream_t stream) {
    const float* features = (const float*)d_in[0];
    const int*   coords   = (const int*)d_in[1];
    const float* w1 = (const float*)d_in[2];
    const float* b1 = (const float*)d_in[3];
    const float* w2 = (const float*)d_in[4];
    const float* b2 = (const float*)d_in[5];
    const float* wd = (const float*)d_in[6];
    float* out = (float*)d_out;

    char* ws = (char*)d_ws;
    int*            grid   = (int*)ws;                           //  3,276,800 B
    int*            nbrp   = (int*)(ws + 3276800);               // 13,107,200 B (8 taps)
    int*            ord    = (int*)(ws + 16384000);              //  1,638,400 B
    __hip_bfloat16* fpermb = (__hip_bfloat16*)(ws + 18022400);   // 52,428,800 B
    __hip_bfloat16* y1     = (__hip_bfloat16*)(ws + 70451200);   // 52,428,800 B
    __hip_bfloat16* wc1    = (__hip_bfloat16*)(ws + 122880000);  //     73,728 B
    __hip_bfloat16* wc2    = (__hip_bfloat16*)(ws + 122953728);  //     81,920 B
    // total 123,035,648 B (same as round-0 budget)
    // lsort + hist live in y1's region (dead until conv1 writes y1)
    int* lsort = (int*)(ws + 70451200);                          //  1,638,400 B
    int* hist  = (int*)(ws + 70451200 + 1638400);                //     12,800 B

    hipMemsetAsync(grid, 0xFF, (size_t)HW * 2 * sizeof(int), stream);   // grid = -1
    hipMemsetAsync(hist, 0x00, (size_t)NTILE * sizeof(int), stream);

    hist_kernel          <<<1600,  256, 0, stream>>>(coords, hist);
    scan_kernel          <<<1,     256, 0, stream>>>(hist);
    ord_kernel           <<<1600,  256, 0, stream>>>(coords, hist, ord, lsort);
    cast_w_kernel        <<<304,   256, 0, stream>>>(w1, w2, wd, wc1, wc2);
    scatter_sorted_kernel<<<1600,  256, 0, stream>>>(lsort, grid);
    nbr_kernel           <<<1600,  256, 0, stream>>>(lsort, grid, nbrp);
    perm_cast_kernel     <<<12800, 256, 0, stream>>>(features, ord, fpermb);

    conv_kernel<false><<<3200, 256, 0, stream>>>(fpermb, nullptr, nbrp, ord, wc1, b1, y1, nullptr);
    conv_kernel<true ><<<3200, 256, 0, stream>>>(y1, fpermb, nbrp, ord, wc2, b2, nullptr, out);
}

// Round 3
// 422.225 us; speedup vs baseline: 1.4101x; 1.4101x over previous
//
#include <hip/hip_runtime.h>
#include <hip/hip_bf16.h>
#include <stdint.h>

#define NP 409600
#define HG 640
#define WG 640
#define HW (HG*WG)
// spatial tiles: 16x16 cells, ~50% density => ~128 points/tile = one conv block
#define TPB  40          // tiles per axis (640/16)
#define NTILE 3200       // 2 * 40 * 40

typedef __bf16 bf16x8 __attribute__((ext_vector_type(8)));
typedef float f32x4 __attribute__((ext_vector_type(4)));

// ---------------- prep kernels ----------------

// counting sort by spatial tile: hist -> exclusive scan -> scatter order
__global__ void hist_kernel(const int* __restrict__ coords, int* __restrict__ hist) {
    int i = blockIdx.x * 256 + threadIdx.x;
    int b = coords[3*i], y = coords[3*i+1], x = coords[3*i+2];
    atomicAdd(&hist[b*(TPB*TPB) + (y>>4)*TPB + (x>>4)], 1);
}

__global__ void scan_kernel(int* __restrict__ hist) {   // 1 block, 256 threads, 13 vals each
    __shared__ int part[256];
    int t = threadIdx.x;
    int loc[13];
    int s = 0;
    #pragma unroll
    for (int k = 0; k < 13; ++k) {
        int idx = t*13 + k;
        int v = (idx < NTILE) ? hist[idx] : 0;
        loc[k] = s; s += v;
    }
    part[t] = s;
    __syncthreads();
    for (int off = 1; off < 256; off <<= 1) {   // Hillis-Steele inclusive scan
        int v = (t >= off) ? part[t - off] : 0;
        __syncthreads();
        part[t] += v;
        __syncthreads();
    }
    int pre = (t > 0) ? part[t-1] : 0;
    #pragma unroll
    for (int k = 0; k < 13; ++k) {
        int idx = t*13 + k;
        if (idx < NTILE) hist[idx] = pre + loc[k];
    }
}

// ord[pos] = original point id; lsort[pos] = packed linear coord
__global__ void ord_kernel(const int* __restrict__ coords, int* __restrict__ offs,
                           int* __restrict__ ord, int* __restrict__ lsort) {
    int i = blockIdx.x * 256 + threadIdx.x;
    int b = coords[3*i], y = coords[3*i+1], x = coords[3*i+2];
    int tile = b*(TPB*TPB) + (y>>4)*TPB + (x>>4);
    int pos = atomicAdd(&offs[tile], 1);
    ord[pos]   = i;
    lsort[pos] = b*HW + y*WG + x;
}

// grid[lin] = SORTED position (so nbr table holds sorted positions)
__global__ void scatter_sorted_kernel(const int* __restrict__ lsort, int* __restrict__ grid) {
    int j = blockIdx.x * 256 + threadIdx.x;
    grid[lsort[j]] = j;
}

// permute + cast: fpermb[j] = bf16(features[ord[j]]); 8 threads per row
__global__ void perm_cast_kernel(const float* __restrict__ f, const int* __restrict__ ord,
                                 __hip_bfloat16* __restrict__ fpermb) {
    int t = blockIdx.x * 256 + threadIdx.x;       // grid = 12800 blocks
    int j = t >> 3, part = t & 7;
    int i = ord[j];
    const float4* p = (const float4*)(f + (long)i*64 + part*8);
    float4 a = p[0], b = p[1];
    union { uint4 q; __hip_bfloat16 h[8]; } u;
    u.h[0] = __float2bfloat16(a.x); u.h[1] = __float2bfloat16(a.y);
    u.h[2] = __float2bfloat16(a.z); u.h[3] = __float2bfloat16(a.w);
    u.h[4] = __float2bfloat16(b.x); u.h[5] = __float2bfloat16(b.y);
    u.h[6] = __float2bfloat16(b.z); u.h[7] = __float2bfloat16(b.w);
    *(uint4*)(fpermb + (long)j*64 + part*8) = u.q;
}

// neighbor table over SORTED order j; center tap (tt==4) omitted (always self).
// values are SORTED positions (index fpermb / y1 directly)
__global__ void nbr_kernel(const int* __restrict__ lsort, const int* __restrict__ grid,
                           int* __restrict__ nbrp) {
    int j = blockIdx.x * 256 + threadIdx.x;
    int lin = lsort[j];
    int b = lin / HW;
    int rem = lin - b*HW;
    int y = rem / WG;
    int x = rem - y*WG;
    int baseg = b*HW;
    #pragma unroll
    for (int tt = 0; tt < 9; ++tt) {
        if (tt == 4) continue;
        int ti = tt < 4 ? tt : tt - 1;
        int ny = y + tt/3 - 1, nx = x + tt%3 - 1;
        int g = -1;
        if (ny >= 0 && ny < HG && nx >= 0 && nx < WG)
            g = grid[baseg + ny*WG + nx];
        nbrp[ti*NP + j] = g;
    }
}

// weights pre-cast to bf16 and transposed to [tap][n=out_ch][k=in_ch]
__global__ void cast_w_kernel(const float* __restrict__ w1, const float* __restrict__ w2,
                              const float* __restrict__ wd,
                              __hip_bfloat16* __restrict__ wc1, __hip_bfloat16* __restrict__ wc2) {
    int i = blockIdx.x * 256 + threadIdx.x;   // grid = 77824 threads exactly
    if (i < 9*4096) {
        int t = i >> 12, r = i & 4095, n = r >> 6, k = r & 63;
        wc1[i] = __float2bfloat16(w1[(t << 12) + (k << 6) + n]);
    }
    int j = i - 9*4096;
    if (j >= 0 && j < 10*4096) {
        int t = j >> 12, r = j & 4095, n = r >> 6, k = r & 63;
        float v = (t < 9) ? w2[(t << 12) + (k << 6) + n] : wd[(k << 6) + n];
        wc2[j] = __float2bfloat16(v);
    }
}

// ---------------- gather-GEMM conv kernel ----------------
// Tile: 128 sorted rows x 64 cols per block, 256 threads = 4 waves.
// Data is in SORTED order (fpermb / y1) so gathers are L2-local.
// Round-0 staging structure (no register state held across the MFMA block,
// except the NEXT tap's neighbor index: 1 VGPR). Center tap (t==4) and the
// FINAL identity tap read contiguous rows.
// FINAL: tap 9 = identity(fpermb) @ wd into separate accR (reference applies
// relu(conv2+b2) BEFORE adding the residual).

#define LDA 72
#define LDB 72

template<bool FINAL>
__launch_bounds__(256)
__global__ void conv_kernel(const __hip_bfloat16* __restrict__ src,    // sorted-order gather source
                            const __hip_bfloat16* __restrict__ idsrc,  // identity source (FINAL)
                            const int* __restrict__ nbrp,              // [8][NP] sorted positions
                            const int* __restrict__ ord,               // sorted pos -> orig id
                            const __hip_bfloat16* __restrict__ wT,     // [NTAP][64][64] (n,k)
                            const float* __restrict__ bias,
                            __hip_bfloat16* __restrict__ out_bf,       // sorted order (conv1)
                            float* __restrict__ out_f) {               // original order (conv2)
    __shared__ __align__(16) __hip_bfloat16 As[128 * LDA];
    __shared__ __align__(16) __hip_bfloat16 Bs[64 * LDB];

    const int tid = threadIdx.x;
    // XCD-aware swizzle: 3200 blocks, 8 XCDs, 400 contiguous spatial tiles per XCD
    const int sbid = (blockIdx.x & 7) * 400 + (blockIdx.x >> 3);
    const int base = sbid * 128;
    const int wave = tid >> 6, lane = tid & 63;
    const int srow = tid >> 1, shalf = tid & 1;   // staging: 2 threads per row

    f32x4 acc[2][4];
    f32x4 accR[2][4];
    #pragma unroll
    for (int i = 0; i < 2; ++i)
        #pragma unroll
        for (int j = 0; j < 4; ++j) {
            acc[i][j]  = (f32x4){0.f, 0.f, 0.f, 0.f};
            accR[i][j] = (f32x4){0.f, 0.f, 0.f, 0.f};
        }

    const int NT = FINAL ? 10 : 9;

    // neighbor position for tap t (sorted space); t==4 is self (contiguous)
    auto gpos = [&](int t) -> int {
        if (t == 4) return base + srow;
        int ti = t < 4 ? t : t - 1;
        return nbrp[ti*NP + base + srow];
    };

    auto do_mfma = [&](f32x4 (&ac)[2][4]) {
        #pragma unroll
        for (int ks = 0; ks < 2; ++ks) {
            int kb = ks*32 + (lane >> 4)*8;
            bf16x8 a0 = *(const bf16x8*)(As + (wave*32      + (lane & 15))*LDA + kb);
            bf16x8 a1 = *(const bf16x8*)(As + (wave*32 + 16 + (lane & 15))*LDA + kb);
            bf16x8 b0 = *(const bf16x8*)(Bs + ( 0 + (lane & 15))*LDB + kb);
            bf16x8 b1 = *(const bf16x8*)(Bs + (16 + (lane & 15))*LDB + kb);
            bf16x8 b2 = *(const bf16x8*)(Bs + (32 + (lane & 15))*LDB + kb);
            bf16x8 b3 = *(const bf16x8*)(Bs + (48 + (lane & 15))*LDB + kb);
            ac[0][0] = __builtin_amdgcn_mfma_f32_16x16x32_bf16(a0, b0, ac[0][0], 0, 0, 0);
            ac[0][1] = __builtin_amdgcn_mfma_f32_16x16x32_bf16(a0, b1, ac[0][1], 0, 0, 0);
            ac[0][2] = __builtin_amdgcn_mfma_f32_16x16x32_bf16(a0, b2, ac[0][2], 0, 0, 0);
            ac[0][3] = __builtin_amdgcn_mfma_f32_16x16x32_bf16(a0, b3, ac[0][3], 0, 0, 0);
            ac[1][0] = __builtin_amdgcn_mfma_f32_16x16x32_bf16(a1, b0, ac[1][0], 0, 0, 0);
            ac[1][1] = __builtin_amdgcn_mfma_f32_16x16x32_bf16(a1, b1, ac[1][1], 0, 0, 0);
            ac[1][2] = __builtin_amdgcn_mfma_f32_16x16x32_bf16(a1, b2, ac[1][2], 0, 0, 0);
            ac[1][3] = __builtin_amdgcn_mfma_f32_16x16x32_bf16(a1, b3, ac[1][3], 0, 0, 0);
        }
    };

    int g = gpos(0);   // tap-0 neighbor index prefetched

    for (int t = 0; t < NT; ++t) {
        if (t) __syncthreads();   // WAR: previous tap's mfma reads done

        // ---- stage A: gather 128 rows x 64 bf16 (zero-fill invalid) ----
        const __hip_bfloat16* sp = (FINAL && t == NT - 1) ? idsrc : src;
        uint4 v0, v1, v2, v3;
        if (g >= 0) {
            const uint4* p = (const uint4*)(sp + (long)g*64 + shalf*32);
            v0 = p[0]; v1 = p[1]; v2 = p[2]; v3 = p[3];
        } else {
            v0 = v1 = v2 = v3 = make_uint4(0u, 0u, 0u, 0u);
        }
        uint4* dst = (uint4*)(As + srow*LDA + shalf*32);
        dst[0] = v0; dst[1] = v1; dst[2] = v2; dst[3] = v3;

        // ---- stage B: 64x64 bf16 weight tap ----
        const uint4* wp = (const uint4*)(wT + t*4096);
        #pragma unroll
        for (int jj = 0; jj < 2; ++jj) {
            int e = tid + jj*256;          // uint4 index 0..511
            int l = e * 8;
            int n = l >> 6, k = l & 63;
            *(uint4*)(Bs + n*LDB + k) = wp[e];
        }
        __syncthreads();

        // prefetch next tap's neighbor INDEX only (1 VGPR across the MFMAs)
        if (t + 1 < NT)
            g = (FINAL && t + 1 == NT - 1) ? (base + srow) : gpos(t + 1);

        if (FINAL && t == NT - 1) do_mfma(accR);
        else                      do_mfma(acc);
    }

    // ---- epilogue ----
    const int col = lane & 15, quad = lane >> 4;
    #pragma unroll
    for (int cb = 0; cb < 4; ++cb) {
        float bv = bias[cb*16 + col];
        #pragma unroll
        for (int mb = 0; mb < 2; ++mb) {
            #pragma unroll
            for (int r = 0; r < 4; ++r) {
                float v = acc[mb][cb][r] + bv;
                v = v > 0.f ? v : 0.f;
                int srt = base + wave*32 + mb*16 + quad*4 + r;   // sorted row
                int c   = cb*16 + col;
                if (FINAL) {
                    v += accR[mb][cb][r];      // residual added AFTER inner relu
                    v = v > 0.f ? v : 0.f;
                    long row = ord[srt];       // scatter to original order
                    out_f[row*64 + c] = v;
                } else {
                    out_bf[(long)srt*64 + c] = __float2bfloat16(v);   // stay sorted
                }
            }
        }
    }
}

// ---------------- launch ----------------

extern "C" void kernel_launch(void* const* d_in, const int* in_sizes, int n_in,
                              void* d_out, int out_size, void* d_ws, size_t ws_size,
                              hipStream_t stream) {
    const float* features = (const float*)d_in[0];
    const int*   coords   = (const int*)d_in[1];
    const float* w1 = (const float*)d_in[2];
    const float* b1 = (const float*)d_in[3];
    const float* w2 = (const float*)d_in[4];
    const float* b2 = (const float*)d_in[5];
    const float* wd = (const float*)d_in[6];
    float* out = (float*)d_out;

    char* ws = (char*)d_ws;
    int*            grid   = (int*)ws;                           //  3,276,800 B
    int*            nbrp   = (int*)(ws + 3276800);               // 13,107,200 B (8 taps)
    int*            ord    = (int*)(ws + 16384000);              //  1,638,400 B
    __hip_bfloat16* fpermb = (__hip_bfloat16*)(ws + 18022400);   // 52,428,800 B
    __hip_bfloat16* y1     = (__hip_bfloat16*)(ws + 70451200);   // 52,428,800 B
    __hip_bfloat16* wc1    = (__hip_bfloat16*)(ws + 122880000);  //     73,728 B
    __hip_bfloat16* wc2    = (__hip_bfloat16*)(ws + 122953728);  //     81,920 B
    // total 123,035,648 B
    // lsort + hist live in y1's region (dead until conv1 writes y1)
    int* lsort = (int*)(ws + 70451200);                          //  1,638,400 B
    int* hist  = (int*)(ws + 70451200 + 1638400);                //     12,800 B

    hipMemsetAsync(grid, 0xFF, (size_t)HW * 2 * sizeof(int), stream);   // grid = -1
    hipMemsetAsync(hist, 0x00, (size_t)NTILE * sizeof(int), stream);

    hist_kernel          <<<1600,  256, 0, stream>>>(coords, hist);
    scan_kernel          <<<1,     256, 0, stream>>>(hist);
    ord_kernel           <<<1600,  256, 0, stream>>>(coords, hist, ord, lsort);
    cast_w_kernel        <<<304,   256, 0, stream>>>(w1, w2, wd, wc1, wc2);
    scatter_sorted_kernel<<<1600,  256, 0, stream>>>(lsort, grid);
    nbr_kernel           <<<1600,  256, 0, stream>>>(lsort, grid, nbrp);
    perm_cast_kernel     <<<12800, 256, 0, stream>>>(features, ord, fpermb);

    conv_kernel<false><<<3200, 256, 0, stream>>>(fpermb, nullptr, nbrp, ord, wc1, b1, y1, nullptr);
    conv_kernel<true ><<<3200, 256, 0, stream>>>(y1, fpermb, nbrp, ord, wc2, b2, nullptr, out);
}